// Round 17
// baseline (2553.186 us; speedup 1.0000x reference)
//
#include <hip/hip_runtime.h>

// ---------------------------------------------------------------------------
// Problem constants
// ---------------------------------------------------------------------------
static constexpr int LSEQ = 512;   // timesteps
static constexpr int NB   = 256;   // batch
static constexpr int CIN  = 256;   // input dim
static constexpr int HD   = 512;   // hidden dim
static constexpr int G3   = 1536;  // 3*HD
static constexpr int NOUT = 256;   // output dim

typedef __attribute__((ext_vector_type(8))) short bf16x8;
typedef __attribute__((ext_vector_type(4))) float f32x4;
typedef __attribute__((ext_vector_type(8))) unsigned short u16x8;
typedef __attribute__((ext_vector_type(4))) unsigned u32x4;

#define DEVI __device__ __forceinline__

DEVI float b2f(unsigned short h) { return __uint_as_float(((unsigned)h) << 16); }
DEVI unsigned short f2b(float x) {
    unsigned u = __float_as_uint(x);
    return (unsigned short)((u + 0x7FFFu + ((u >> 16) & 1u)) >> 16);
}

// LLC-coherent (cross-XCD safe) dword access — THE validated flavor.
DEVI unsigned cload(const unsigned* p) {
    return __hip_atomic_load(p, __ATOMIC_RELAXED, __HIP_MEMORY_SCOPE_AGENT);
}
DEVI void cstore(unsigned* p, unsigned v) {
    __hip_atomic_store(p, v, __ATOMIC_RELAXED, __HIP_MEMORY_SCOPE_AGENT);
}

DEVI float sigm(float v) { return 1.f / (1.f + __expf(-v)); }
DEVI float fast_tanh(float x) {
    x = fminf(10.f, fmaxf(-10.f, x));
    float e = __expf(-2.f * x);
    return (1.f - e) / (1.f + e);
}

// 4x coherent 16B loads (LLC), one waitcnt. sched_barrier guards against the
// compiler hoisting register-only consumers past the inline-asm waitcnt.
DEVI void cload4x4(const unsigned* p0, const unsigned* p1,
                   const unsigned* p2, const unsigned* p3,
                   u32x4& r0, u32x4& r1, u32x4& r2, u32x4& r3) {
    asm volatile(
        "global_load_dwordx4 %0, %4, off sc0 sc1\n\t"
        "global_load_dwordx4 %1, %5, off sc0 sc1\n\t"
        "global_load_dwordx4 %2, %6, off sc0 sc1\n\t"
        "global_load_dwordx4 %3, %7, off sc0 sc1\n\t"
        "s_waitcnt vmcnt(0)"
        : "=&v"(r0), "=&v"(r1), "=&v"(r2), "=&v"(r3)
        : "v"(p0), "v"(p1), "v"(p2), "v"(p3)
        : "memory");
    __builtin_amdgcn_sched_barrier(0);
}

// ---------------------------------------------------------------------------
// Float-dtype detection (f32 vs bf16 harness data).
// ---------------------------------------------------------------------------
__global__ void detect_fdt(const unsigned short* __restrict__ x, int nHalf,
                           unsigned* __restrict__ fdt) {
    __shared__ unsigned big;
    if (threadIdx.x == 0) big = 0;
    __syncthreads();
    for (int i = threadIdx.x; i < nHalf; i += 256) {
        unsigned e = (x[i] >> 7) & 0xFFu;
        if (e >= 0xC0u) atomicOr(&big, 1u);
    }
    __syncthreads();
    if (threadIdx.x == 0) *fdt = big ? 1u : 0u;
}

__global__ void cast_bf16(const void* __restrict__ src, long srcOff,
                          unsigned short* __restrict__ dst, long n,
                          const unsigned* __restrict__ fdt) {
    long i = (long)blockIdx.x * 256 + threadIdx.x;
    long stride = (long)gridDim.x * 256;
    if (*fdt) {
        const float* s = (const float*)src + srcOff;
        for (; i < n; i += stride) dst[i] = f2b(s[i]);
    } else {
        const unsigned short* s = (const unsigned short*)src + srcOff;
        for (; i < n; i += stride) dst[i] = s[i];
    }
}

__global__ void detect_done(const unsigned char* __restrict__ d, int elems,
                            unsigned* __restrict__ flag) {
    __shared__ unsigned bad[4];
    int tid = threadIdx.x;
    if (tid < 4) bad[tid] = 0;
    __syncthreads();
    int nInt = elems >> 2;
    const unsigned* di = (const unsigned*)d;
    for (int i = tid; i < nInt; i += 256) {
        unsigned v = di[i];
        if (v > 1u) atomicOr(&bad[0], 1u);
        if (v != 0u && v != 0x3F800000u) atomicOr(&bad[1], 1u);
    }
    int nHalf = elems >> 1;
    const unsigned short* dh = (const unsigned short*)d;
    for (int i = tid; i < nHalf; i += 256) {
        unsigned short h = dh[i];
        if (h != 0 && h != 0x3F80) atomicOr(&bad[2], 1u);
    }
    __syncthreads();
    if (tid == 0) {
        unsigned f;
        if (!bad[0]) f = 0u;
        else if (!bad[1]) f = 3u;
        else if (!bad[2]) f = 2u;
        else f = 1u;
        *flag = f;
    }
}

__global__ void expand_done(const void* __restrict__ d, const unsigned* __restrict__ flag,
                            float* __restrict__ keep, int elems) {
    int i = blockIdx.x * 256 + threadIdx.x;
    if (i >= elems) return;
    unsigned f = *flag;
    float v;
    if (f == 0u)      v = (float)((const int*)d)[i];
    else if (f == 1u) v = (float)((const unsigned char*)d)[i];
    else if (f == 2u) v = b2f(((const unsigned short*)d)[i]);
    else              v = ((const float*)d)[i];
    keep[i] = 1.f - v;
}

// ---------------------------------------------------------------------------
// NT GEMM (projection only): C[M,N] = A[M,K]@B[N,K]^T + bias.
// ---------------------------------------------------------------------------
__global__ __launch_bounds__(256) void gemm_nt(
    const unsigned short* __restrict__ A, const unsigned short* __restrict__ B,
    const unsigned short* __restrict__ bias, unsigned short* __restrict__ C,
    float* __restrict__ Cf, const unsigned* __restrict__ fdt,
    int M, int N, int K) {
    __shared__ unsigned short sm[16384];
    const int tid = threadIdx.x;
    const int l = tid & 63, w = tid >> 6;
    const int lr = l & 15, lq = l >> 4;
    const int wr = w >> 1, wc = w & 1;
    const long rowBase = (long)blockIdx.y * 128;
    const long colBase = (long)blockIdx.x * 128;

    int qrow[4], qc8[4];
#pragma unroll
    for (int i = 0; i < 4; i++) {
        int q = (i * 4 + w) * 64 + l;
        qrow[i] = q >> 3;
        qc8[i] = (q & 7) * 8;
    }

    f32x4 acc[4][4] = {};

    for (int k0 = 0; k0 < K; k0 += 64) {
#pragma unroll
        for (int i = 0; i < 4; i++) {
            const unsigned short* sA = A + (rowBase + qrow[i]) * K + k0 + qc8[i];
            const unsigned short* sB = B + (colBase + qrow[i]) * K + k0 + qc8[i];
            __builtin_amdgcn_global_load_lds(
                (const __attribute__((address_space(1))) void*)sA,
                (__attribute__((address_space(3))) void*)(sm + (i * 4 + w) * 512), 16, 0, 0);
            __builtin_amdgcn_global_load_lds(
                (const __attribute__((address_space(1))) void*)sB,
                (__attribute__((address_space(3))) void*)(sm + 8192 + (i * 4 + w) * 512), 16, 0, 0);
        }
        __syncthreads();
#pragma unroll
        for (int ks = 0; ks < 2; ks++) {
            bf16x8 af[4], bfr[4];
#pragma unroll
            for (int mi = 0; mi < 4; mi++)
                af[mi] = *(const bf16x8*)&sm[(wr * 64 + mi * 16 + lr) * 64 + ks * 32 + lq * 8];
#pragma unroll
            for (int ni = 0; ni < 4; ni++)
                bfr[ni] = *(const bf16x8*)&sm[8192 + (wc * 64 + ni * 16 + lr) * 64 + ks * 32 + lq * 8];
#pragma unroll
            for (int mi = 0; mi < 4; mi++)
#pragma unroll
                for (int ni = 0; ni < 4; ni++)
                    acc[mi][ni] = __builtin_amdgcn_mfma_f32_16x16x32_bf16(
                        af[mi], bfr[ni], acc[mi][ni], 0, 0, 0);
        }
        __syncthreads();
    }

    float bv[4];
#pragma unroll
    for (int ni = 0; ni < 4; ni++)
        bv[ni] = bias ? b2f(bias[colBase + wc * 64 + ni * 16 + lr]) : 0.f;

    const bool f32out = (fdt != nullptr) && (*fdt != 0u);
    if (f32out) {
#pragma unroll
        for (int mi = 0; mi < 4; mi++)
#pragma unroll
            for (int ni = 0; ni < 4; ni++)
#pragma unroll
                for (int rg = 0; rg < 4; rg++) {
                    int m = wr * 64 + mi * 16 + lq * 4 + rg;
                    int n = wc * 64 + ni * 16 + lr;
                    Cf[(rowBase + m) * (long)N + colBase + n] = acc[mi][ni][rg] + bv[ni];
                }
        return;
    }

#pragma unroll
    for (int mi = 0; mi < 4; mi++)
#pragma unroll
        for (int ni = 0; ni < 4; ni++)
#pragma unroll
            for (int rg = 0; rg < 4; rg++) {
                int m = wr * 64 + mi * 16 + lq * 4 + rg;
                int n = wc * 64 + ni * 16 + lr;
                sm[m * 128 + n] = f2b(acc[mi][ni][rg] + bv[ni]);
            }
    __syncthreads();
#pragma unroll
    for (int i = 0; i < 8; i++) {
        int idx = i * 2048 + tid * 8;
        int r = idx >> 7, c = idx & 127;
        *(u16x8*)(C + (rowBase + r) * N + colBase + c) = *(const u16x8*)&sm[idx];
    }
}

// ---------------------------------------------------------------------------
// GRU recurrence body with FUSED input GEMM (gi = v@Wih computed in-step).
// KV = input width (256 for L0/x, 512 for L1/y0). v-operand loads are PLAIN
// (cross-dispatch data, cached) prefetched in the overlap window. Gate accs:
// [0..3]=rz(g,cf) shared ih+hh, [4..5]=n_h(cf), [6..7]=n_x(cf) (r7-verified).
// Skeleton (barrier/h-exchange) = r13/r15 verbatim.
// ---------------------------------------------------------------------------
template <int KV>
DEVI void gru_body(
    const void* __restrict__ vin,            // [.][NB][KV] f32(flag) or bf16
    int vF32, int vT0off,                    // v index = (t - vT0off)
    const unsigned short* __restrict__ wih,  // [G3][KV] bf16 staged
    const unsigned short* __restrict__ whh,  // [G3][HD]
    const unsigned short* __restrict__ bih, const unsigned short* __restrict__ bhh,
    const float* __restrict__ keep, const unsigned short* __restrict__ mem,
    unsigned short* __restrict__ hdb, unsigned short* __restrict__ Y,
    unsigned short* __restrict__ hnB, float* __restrict__ hnF,
    bool f32out, int t0, int Tc, int layerOff,
    unsigned* __restrict__ ctr, int lb, float (*red)[16][132]) {
    constexpr int KVR = KV / 128;            // bf16x8 fragments per wave (2 or 4)
    const int tid = threadIdx.x;
    const int l = tid & 63, w = tid >> 6, lr = l & 15, lq = l >> 4;
    const int bi = lb & 15, bj = lb >> 4;

    // --- weight fragments -> registers (one-time) ---
    bf16x8 wreg[6][4], wi[6][KVR];
#pragma unroll
    for (int fr = 0; fr < 6; fr++) {
        int g = fr >> 1, cf = fr & 1;
        long row = (long)g * HD + bj * 32 + cf * 16 + lr;
#pragma unroll
        for (int ks = 0; ks < 4; ks++) {
            int k = w * 128 + ks * 32 + lq * 8;
            wreg[fr][ks] = *(const bf16x8*)(whh + row * HD + k);
        }
#pragma unroll
        for (int ks = 0; ks < KVR; ks++) {
            int k2 = w * (KV / 4) + ks * 32 + lq * 8;
            wi[fr][ks] = *(const bf16x8*)(wih + row * KV + k2);
        }
    }

    const int m = tid >> 4, c0 = (tid & 15) * 2;
    const int n_g = bi * 16 + m;
    const int ch = bj * 32 + c0;
    float brz[2][2], bnx[2], bnh[2];
#pragma unroll
    for (int g = 0; g < 2; g++)
#pragma unroll
        for (int j = 0; j < 2; j++)
            brz[g][j] = b2f(bih[g * HD + ch + j]) + b2f(bhh[g * HD + ch + j]);
#pragma unroll
    for (int j = 0; j < 2; j++) {
        bnx[j] = b2f(bih[2 * HD + ch + j]);
        bnh[j] = b2f(bhh[2 * HD + ch + j]);
    }

    if (t0 == 0) {  // init h0 from memory (layer slice) into parity 0
        unsigned v = *(const unsigned*)(mem + (long)n_g * 1024 + layerOff + ch);
        cstore((unsigned*)(hdb + (long)n_g * HD + ch), v);
        unsigned* islot = ctr + ((long)Tc * 16 + bi) * 32;
        __syncthreads();
        if (tid == 0) {
            __hip_atomic_fetch_add(islot, 1u, __ATOMIC_RELAXED, __HIP_MEMORY_SCOPE_AGENT);
            while (__hip_atomic_load(islot, __ATOMIC_RELAXED, __HIP_MEMORY_SCOPE_AGENT) < 16u)
                __builtin_amdgcn_s_sleep(1);
        }
        __syncthreads();
    }

    float hpv[2];
    {
        unsigned hp0 = cload((const unsigned*)(hdb + (long)(t0 & 1) * NB * HD + (long)n_g * HD + ch));
        hpv[0] = b2f((unsigned short)(hp0 & 0xffffu));
        hpv[1] = b2f((unsigned short)(hp0 >> 16));
    }

    // v-fragment loader (plain cached loads; f32 path converts in-register)
    auto loadV = [&](int t, bf16x8* vf) {
        long rowoff = ((long)(t - vT0off) * NB + bi * 16 + lr);
        int kb = w * (KV / 4) + lq * 8;
        if (!vF32) {
            const unsigned short* vp = (const unsigned short*)vin + rowoff * KV + kb;
#pragma unroll
            for (int i = 0; i < KVR; i++) vf[i] = *(const bf16x8*)(vp + i * 32);
        } else {
            const float* vp = (const float*)vin + rowoff * KV + kb;
#pragma unroll
            for (int i = 0; i < KVR; i++) {
                f32x4 a = *(const f32x4*)(vp + i * 32);
                f32x4 b = *(const f32x4*)(vp + i * 32 + 4);
#pragma unroll
                for (int e = 0; e < 4; e++) {
                    ((unsigned short*)&vf[i])[e]     = f2b(a[e]);
                    ((unsigned short*)&vf[i])[4 + e] = f2b(b[e]);
                }
            }
        }
    };

    // prefetch v/keep for first step
    bf16x8 vf[KVR];
    float kp;
    loadV(t0, vf);
    kp = keep[(long)t0 * NB + n_g];

    for (int t = t0; t < t0 + Tc; ++t) {
        const unsigned short* hc = hdb + (long)(t & 1) * NB * HD;
        unsigned short* hx = hdb + (long)((t + 1) & 1) * NB * HD;

        // coherent 16B loads of the h stripe (written by other blocks)
        const unsigned* hrow = (const unsigned*)(hc + (long)(bi * 16 + lr) * HD);
        union { u32x4 u; bf16x8 v; } t0u, t1u, t2u, t3u;
        cload4x4(hrow + w * 64 + 0 * 16 + lq * 4, hrow + w * 64 + 1 * 16 + lq * 4,
                 hrow + w * 64 + 2 * 16 + lq * 4, hrow + w * 64 + 3 * 16 + lq * 4,
                 t0u.u, t1u.u, t2u.u, t3u.u);
        bf16x8 af[4] = { t0u.v, t1u.v, t2u.v, t3u.v };

        f32x4 acc[8] = {};
#pragma unroll
        for (int ks = 0; ks < 4; ks++)
#pragma unroll
            for (int fr = 0; fr < 6; fr++) {
                int g = fr >> 1, cf = fr & 1;
                int dst = (g < 2) ? fr : (4 + cf);
                acc[dst] = __builtin_amdgcn_mfma_f32_16x16x32_bf16(af[ks], wreg[fr][ks], acc[dst], 0, 0, 0);
            }
#pragma unroll
        for (int ks = 0; ks < KVR; ks++)
#pragma unroll
            for (int fr = 0; fr < 6; fr++) {
                int g = fr >> 1, cf = fr & 1;
                int dst = (g < 2) ? fr : (6 + cf);
                acc[dst] = __builtin_amdgcn_mfma_f32_16x16x32_bf16(vf[ks], wi[fr][ks], acc[dst], 0, 0, 0);
            }

#pragma unroll
        for (int f = 0; f < 8; f++)
#pragma unroll
            for (int rg = 0; rg < 4; rg++)
                red[w][lq * 4 + rg][f * 16 + lr] = acc[f][rg];
        __syncthreads();

        float sr[2] = {0, 0}, sz[2] = {0, 0}, snh[2] = {0, 0}, snx[2] = {0, 0};
#pragma unroll
        for (int ww = 0; ww < 4; ww++) {
            const float* p = &red[ww][m][0];
            sr[0] += p[c0];       sr[1] += p[c0 + 1];
            sz[0] += p[32 + c0];  sz[1] += p[33 + c0];
            snh[0] += p[64 + c0]; snh[1] += p[65 + c0];
            snx[0] += p[96 + c0]; snx[1] += p[97 + c0];
        }

        unsigned short yo[2], ho[2];
        float hcf[2];
#pragma unroll
        for (int j = 0; j < 2; j++) {
            float r = sigm(sr[j] + brz[0][j]);
            float z = sigm(sz[j] + brz[1][j]);
            float nn = fast_tanh((snx[j] + bnx[j]) + r * (snh[j] + bnh[j]));
            float hnew = (1.f - z) * nn + z * hpv[j];
            hcf[j] = hnew * kp;
            yo[j] = f2b(hnew);
            ho[j] = f2b(hcf[j]);
            hpv[j] = b2f(ho[j]);
        }
        unsigned ypack = (unsigned)yo[0] | ((unsigned)yo[1] << 16);
        unsigned hpack = (unsigned)ho[0] | ((unsigned)ho[1] << 16);

        cstore((unsigned*)(hx + (long)n_g * HD + ch), hpack);  // barrier-gated

        const bool last = (t + 1 >= t0 + Tc);
        unsigned* slot = ctr + ((long)(t - t0) * 16 + bi) * 32;
        if (!last) {
            __syncthreads();  // drains the h cstore
            if (tid == 0)
                __hip_atomic_fetch_add(slot, 1u, __ATOMIC_RELAXED, __HIP_MEMORY_SCOPE_AGENT);
        }

        // non-barrier-gated work, overlapped with group arrival
        *(unsigned*)(Y + ((long)(t - t0) * NB + n_g) * HD + ch) = ypack;
        if (t == LSEQ - 1) {
            if (f32out) {
                hnF[(long)n_g * 1024 + layerOff + ch]     = hcf[0];
                hnF[(long)n_g * 1024 + layerOff + ch + 1] = hcf[1];
            } else {
                *(unsigned*)(hnB + (long)n_g * 1024 + layerOff + ch) = hpack;
            }
        }
        if (!last) {
            loadV(t + 1, vf);                    // plain loads under the poll
            kp = keep[(long)(t + 1) * NB + n_g];
            if (tid == 0) {
                while (__hip_atomic_load(slot, __ATOMIC_RELAXED, __HIP_MEMORY_SCOPE_AGENT) < 16u)
                    __builtin_amdgcn_s_sleep(1);
            }
            __syncthreads();
        }
    }
}

// ---------------------------------------------------------------------------
// Dual-layer dispatch: blocks 0-255 = L0 chunk cA (x-fused), blocks 256-511 =
// L1 chunk cB (y0-fused, reading the Y0 buffer written by the previous dual —
// cross-dispatch, plain cached). Fully independent halves, 2 blocks/CU.
// ---------------------------------------------------------------------------
__global__ __launch_bounds__(256, 2) void gru_dual(
    const void* xin,
    const unsigned short* WIH0, const unsigned short* WHH0,
    const unsigned short* BIH0, const unsigned short* BHH0,
    unsigned short* hdbA, unsigned short* YA, int t0A, unsigned* ctrA, int enA,
    const unsigned short* y0prev,
    const unsigned short* WIH1, const unsigned short* WHH1,
    const unsigned short* BIH1, const unsigned short* BHH1,
    unsigned short* hdbB, unsigned short* YB, int t0B, unsigned* ctrB, int enB,
    const float* keep, const unsigned short* mem,
    unsigned short* hnB, float* hnF, const unsigned* fdt, int Tc) {
    __shared__ float red[4][16][132];
    const bool f32out = (*fdt != 0u);
    const int half = blockIdx.x >> 8;
    const int lb = blockIdx.x & 255;
    if (half == 0) {
        if (enA) gru_body<CIN>(xin, f32out ? 1 : 0, 0, WIH0, WHH0, BIH0, BHH0,
                               keep, mem, hdbA, YA, hnB, hnF, f32out,
                               t0A, Tc, 0, ctrA, lb, red);
    } else {
        if (enB) gru_body<HD>(y0prev, 0, t0B, WIH1, WHH1, BIH1, BHH1,
                              keep, mem, hdbB, YB, hnB, hnF, f32out,
                              t0B, Tc, HD, ctrB, lb, red);
    }
}

// ---------------------------------------------------------------------------
// Host launcher — gi-fused duals + per-iteration projection only.
// ---------------------------------------------------------------------------
extern "C" void kernel_launch(void* const* d_in, const int* in_sizes, int n_in,
                              void* d_out, int out_size, void* d_ws, size_t ws_size,
                              hipStream_t stream) {
    const void* x    = d_in[0];
    const void* mem  = d_in[1];
    const void* done = d_in[2];
    const void* fsrc[11] = { mem, d_in[3], d_in[4], d_in[5], d_in[6],
                             d_in[7], d_in[8], d_in[9], d_in[10], d_in[11], d_in[12] };
    const long  fn[11]   = { (long)NB * 1024, (long)G3 * CIN, (long)G3 * HD, G3, G3,
                             (long)G3 * HD, (long)G3 * HD, G3, G3, (long)NOUT * HD, NOUT };

    unsigned short* outB = (unsigned short*)d_out;
    float*          outF = (float*)d_out;
    unsigned short* hnB  = outB + (size_t)LSEQ * NB * NOUT;
    float*          hnF  = outF + (size_t)LSEQ * NB * NOUT;

    char* ws = (char*)d_ws;
    const size_t oFlag = 0;                                   // fdt @ +0, done-flag @ +64
    const size_t oKeep = 256;
    const size_t oCtr  = oKeep + (size_t)LSEQ * NB * 4;       // 8 MB barrier slots
    const size_t oWC   = oCtr + (size_t)8 * 1024 * 1024;      // staged weights/mem
    size_t wcTot = 0;
    size_t wcOff[11];
    for (int i = 0; i < 11; i++) { wcOff[i] = wcTot; wcTot += (size_t)fn[i] * 2; wcTot = (wcTot + 255) & ~(size_t)255; }
    const size_t oHdb0 = oWC + wcTot;
    const size_t oHdb1 = oHdb0 + (size_t)2 * NB * HD * 2;
    const size_t oDyn  = oHdb1 + (size_t)2 * NB * HD * 2;

    int Tc = 4;
    const int cand[6] = {128, 64, 32, 16, 8, 4};
    for (int i = 0; i < 6; i++) {
        size_t need = oDyn + (size_t)3 * cand[i] * NB * HD * 2;  // Y0A + Y0B + Y1
        if (need <= ws_size) { Tc = cand[i]; break; }
    }
    const size_t oY0A = oDyn;
    const size_t oY0B = oY0A + (size_t)Tc * NB * HD * 2;
    const size_t oY1  = oY0B + (size_t)Tc * NB * HD * 2;

    unsigned*       FDT  = (unsigned*)(ws + oFlag);
    unsigned*       DFLG = (unsigned*)(ws + oFlag + 64);
    float*          KEEP = (float*)(ws + oKeep);
    unsigned*       CTR  = (unsigned*)(ws + oCtr);
    unsigned short* WC   = (unsigned short*)(ws + oWC);
    unsigned short* HDB0 = (unsigned short*)(ws + oHdb0);
    unsigned short* HDB1 = (unsigned short*)(ws + oHdb1);
    unsigned short* Y0A  = (unsigned short*)(ws + oY0A);
    unsigned short* Y0B  = (unsigned short*)(ws + oY0B);
    unsigned short* Y1c  = (unsigned short*)(ws + oY1);

    unsigned short* MEMc = WC + wcOff[0] / 2;
    unsigned short* WIH0 = WC + wcOff[1] / 2;
    unsigned short* WHH0 = WC + wcOff[2] / 2;
    unsigned short* BIH0 = WC + wcOff[3] / 2;
    unsigned short* BHH0 = WC + wcOff[4] / 2;
    unsigned short* WIH1 = WC + wcOff[5] / 2;
    unsigned short* WHH1 = WC + wcOff[6] / 2;
    unsigned short* BIH1 = WC + wcOff[7] / 2;
    unsigned short* BHH1 = WC + wcOff[8] / 2;
    unsigned short* WPc  = WC + wcOff[9] / 2;
    unsigned short* BPc  = WC + wcOff[10] / 2;

    hipMemsetAsync(ws + oCtr, 0, (size_t)8 * 1024 * 1024, stream);
    detect_fdt<<<1, 256, 0, stream>>>((const unsigned short*)x, 4096, FDT);
    detect_done<<<1, 256, 0, stream>>>((const unsigned char*)done, in_sizes[2], DFLG);
    expand_done<<<(LSEQ * NB + 255) / 256, 256, 0, stream>>>(done, DFLG, KEEP, LSEQ * NB);

    for (int i = 0; i < 11; i++) {
        int blocks = (int)((fn[i] + 1023) / 1024);
        if (blocks > 2048) blocks = 2048;
        cast_bf16<<<blocks, 256, 0, stream>>>(fsrc[i], 0, WC + wcOff[i] / 2, fn[i], FDT);
    }

    const int NC = LSEQ / Tc;
    const size_t SZ = (size_t)(Tc + 2) * 16 * 32;  // ctr region dwords per instance

    for (int it = 0; it <= NC; ++it) {
        const int cA = it, cB = it - 1;
        const int enA = (cA < NC) ? 1 : 0;
        const int enB = (cB >= 0) ? 1 : 0;
        unsigned short* YA = (cA & 1) ? Y0B : Y0A;          // L0 writes this chunk
        const unsigned short* VB = (cB & 1) ? Y0B : Y0A;    // L1 reads prev chunk

        gru_dual<<<512, 256, 0, stream>>>(
            x, WIH0, WHH0, BIH0, BHH0, HDB0, YA, cA * Tc,
            CTR + (size_t)(2 * it) * SZ, enA,
            VB, WIH1, WHH1, BIH1, BHH1, HDB1, Y1c, cB * Tc,
            CTR + (size_t)(2 * it + 1) * SZ, enB,
            KEEP, MEMc, hnB, hnF, FDT, Tc);

        if (enB)  // projection of L1 chunk cB
            gemm_nt<<<dim3(NOUT / 128, Tc * NB / 128), 256, 0, stream>>>(
                Y1c, WPc, BPc, outB + (size_t)cB * Tc * NB * NOUT,
                outF + (size_t)cB * Tc * NB * NOUT, FDT, Tc * NB, NOUT, HD);
    }
}

// Round 18
// 2439.649 us; speedup vs baseline: 1.0465x; 1.0465x over previous
//
#include <hip/hip_runtime.h>

// ---------------------------------------------------------------------------
// Problem constants
// ---------------------------------------------------------------------------
static constexpr int LSEQ = 512;   // timesteps
static constexpr int NB   = 256;   // batch
static constexpr int CIN  = 256;   // input dim
static constexpr int HD   = 512;   // hidden dim
static constexpr int G3   = 1536;  // 3*HD
static constexpr int NOUT = 256;   // output dim

typedef __attribute__((ext_vector_type(8))) short bf16x8;
typedef __attribute__((ext_vector_type(4))) float f32x4;
typedef __attribute__((ext_vector_type(8))) unsigned short u16x8;
typedef __attribute__((ext_vector_type(4))) unsigned u32x4;

#define DEVI __device__ __forceinline__

DEVI float b2f(unsigned short h) { return __uint_as_float(((unsigned)h) << 16); }
DEVI unsigned short f2b(float x) {
    unsigned u = __float_as_uint(x);
    return (unsigned short)((u + 0x7FFFu + ((u >> 16) & 1u)) >> 16);
}

// LLC-coherent (cross-XCD safe) dword access — THE validated flavor.
DEVI unsigned cload(const unsigned* p) {
    return __hip_atomic_load(p, __ATOMIC_RELAXED, __HIP_MEMORY_SCOPE_AGENT);
}
DEVI void cstore(unsigned* p, unsigned v) {
    __hip_atomic_store(p, v, __ATOMIC_RELAXED, __HIP_MEMORY_SCOPE_AGENT);
}

// exp-based tanh: no libm branches.
DEVI float fast_tanh(float x) {
    x = fminf(10.f, fmaxf(-10.f, x));
    float e = __expf(-2.f * x);
    return (1.f - e) / (1.f + e);
}

// 4x coherent 16B loads (LLC), one waitcnt. sched_barrier guards against the
// compiler hoisting register-only consumers past the inline-asm waitcnt.
DEVI void cload4x4(const unsigned* p0, const unsigned* p1,
                   const unsigned* p2, const unsigned* p3,
                   u32x4& r0, u32x4& r1, u32x4& r2, u32x4& r3) {
    asm volatile(
        "global_load_dwordx4 %0, %4, off sc0 sc1\n\t"
        "global_load_dwordx4 %1, %5, off sc0 sc1\n\t"
        "global_load_dwordx4 %2, %6, off sc0 sc1\n\t"
        "global_load_dwordx4 %3, %7, off sc0 sc1\n\t"
        "s_waitcnt vmcnt(0)"
        : "=&v"(r0), "=&v"(r1), "=&v"(r2), "=&v"(r3)
        : "v"(p0), "v"(p1), "v"(p2), "v"(p3)
        : "memory");
    __builtin_amdgcn_sched_barrier(0);
}

// ---------------------------------------------------------------------------
// Float-dtype detection (f32 vs bf16 harness data).
// ---------------------------------------------------------------------------
__global__ void detect_fdt(const unsigned short* __restrict__ x, int nHalf,
                           unsigned* __restrict__ fdt) {
    __shared__ unsigned big;
    if (threadIdx.x == 0) big = 0;
    __syncthreads();
    for (int i = threadIdx.x; i < nHalf; i += 256) {
        unsigned e = (x[i] >> 7) & 0xFFu;
        if (e >= 0xC0u) atomicOr(&big, 1u);
    }
    __syncthreads();
    if (threadIdx.x == 0) *fdt = big ? 1u : 0u;
}

__global__ void cast_bf16(const void* __restrict__ src, long srcOff,
                          unsigned short* __restrict__ dst, long n,
                          const unsigned* __restrict__ fdt) {
    long i = (long)blockIdx.x * 256 + threadIdx.x;
    long stride = (long)gridDim.x * 256;
    if (*fdt) {
        const float* s = (const float*)src + srcOff;
        for (; i < n; i += stride) dst[i] = f2b(s[i]);
    } else {
        const unsigned short* s = (const unsigned short*)src + srcOff;
        for (; i < n; i += stride) dst[i] = s[i];
    }
}

__global__ void detect_done(const unsigned char* __restrict__ d, int elems,
                            unsigned* __restrict__ flag) {
    __shared__ unsigned bad[4];
    int tid = threadIdx.x;
    if (tid < 4) bad[tid] = 0;
    __syncthreads();
    int nInt = elems >> 2;
    const unsigned* di = (const unsigned*)d;
    for (int i = tid; i < nInt; i += 256) {
        unsigned v = di[i];
        if (v > 1u) atomicOr(&bad[0], 1u);
        if (v != 0u && v != 0x3F800000u) atomicOr(&bad[1], 1u);
    }
    int nHalf = elems >> 1;
    const unsigned short* dh = (const unsigned short*)d;
    for (int i = tid; i < nHalf; i += 256) {
        unsigned short h = dh[i];
        if (h != 0 && h != 0x3F80) atomicOr(&bad[2], 1u);
    }
    __syncthreads();
    if (tid == 0) {
        unsigned f;
        if (!bad[0]) f = 0u;       // int32 0/1
        else if (!bad[1]) f = 3u;  // float32
        else if (!bad[2]) f = 2u;  // bf16
        else f = 1u;               // bytes (bool / int8)
        *flag = f;
    }
}

__global__ void expand_done(const void* __restrict__ d, const unsigned* __restrict__ flag,
                            float* __restrict__ keep, int elems) {
    int i = blockIdx.x * 256 + threadIdx.x;
    if (i >= elems) return;
    unsigned f = *flag;
    float v;
    if (f == 0u)      v = (float)((const int*)d)[i];
    else if (f == 1u) v = (float)((const unsigned char*)d)[i];
    else if (f == 2u) v = b2f(((const unsigned short*)d)[i]);
    else              v = ((const float*)d)[i];
    keep[i] = 1.f - v;
}

// ---------------------------------------------------------------------------
// GEMM tile body (m97-style) as a device function: C = A@B^T + bias at tile
// (tx,ty). f32 output iff Cf != null AND *fdt (projection segment only).
// ---------------------------------------------------------------------------
DEVI void gemm_tile(
    const unsigned short* __restrict__ A, const unsigned short* __restrict__ B,
    const unsigned short* __restrict__ bias, unsigned short* __restrict__ C,
    float* __restrict__ Cf, const unsigned* __restrict__ fdt,
    int M, int N, int K, int tx, int ty, unsigned short* sm /*16384 shorts*/) {
    const int tid = threadIdx.x;
    const int l = tid & 63, w = tid >> 6;
    const int lr = l & 15, lq = l >> 4;
    const int wr = w >> 1, wc = w & 1;
    const long rowBase = (long)ty * 128;
    const long colBase = (long)tx * 128;

    int qrow[4], qc8[4];
#pragma unroll
    for (int i = 0; i < 4; i++) {
        int q = (i * 4 + w) * 64 + l;
        qrow[i] = q >> 3;
        qc8[i] = (q & 7) * 8;
    }

    f32x4 acc[4][4] = {};

    for (int k0 = 0; k0 < K; k0 += 64) {
#pragma unroll
        for (int i = 0; i < 4; i++) {
            const unsigned short* sA = A + (rowBase + qrow[i]) * K + k0 + qc8[i];
            const unsigned short* sB = B + (colBase + qrow[i]) * K + k0 + qc8[i];
            __builtin_amdgcn_global_load_lds(
                (const __attribute__((address_space(1))) void*)sA,
                (__attribute__((address_space(3))) void*)(sm + (i * 4 + w) * 512), 16, 0, 0);
            __builtin_amdgcn_global_load_lds(
                (const __attribute__((address_space(1))) void*)sB,
                (__attribute__((address_space(3))) void*)(sm + 8192 + (i * 4 + w) * 512), 16, 0, 0);
        }
        __syncthreads();
#pragma unroll
        for (int ks = 0; ks < 2; ks++) {
            bf16x8 af[4], bfr[4];
#pragma unroll
            for (int mi = 0; mi < 4; mi++)
                af[mi] = *(const bf16x8*)&sm[(wr * 64 + mi * 16 + lr) * 64 + ks * 32 + lq * 8];
#pragma unroll
            for (int ni = 0; ni < 4; ni++)
                bfr[ni] = *(const bf16x8*)&sm[8192 + (wc * 64 + ni * 16 + lr) * 64 + ks * 32 + lq * 8];
#pragma unroll
            for (int mi = 0; mi < 4; mi++)
#pragma unroll
                for (int ni = 0; ni < 4; ni++)
                    acc[mi][ni] = __builtin_amdgcn_mfma_f32_16x16x32_bf16(
                        af[mi], bfr[ni], acc[mi][ni], 0, 0, 0);
        }
        __syncthreads();
    }

    float bv[4];
#pragma unroll
    for (int ni = 0; ni < 4; ni++)
        bv[ni] = bias ? b2f(bias[colBase + wc * 64 + ni * 16 + lr]) : 0.f;

    const bool f32out = (Cf != nullptr) && (*fdt != 0u);
    if (f32out) {
#pragma unroll
        for (int mi = 0; mi < 4; mi++)
#pragma unroll
            for (int ni = 0; ni < 4; ni++)
#pragma unroll
                for (int rg = 0; rg < 4; rg++) {
                    int m = wr * 64 + mi * 16 + lq * 4 + rg;
                    int n = wc * 64 + ni * 16 + lr;
                    Cf[(rowBase + m) * (long)N + colBase + n] = acc[mi][ni][rg] + bv[ni];
                }
        return;
    }

#pragma unroll
    for (int mi = 0; mi < 4; mi++)
#pragma unroll
        for (int ni = 0; ni < 4; ni++)
#pragma unroll
            for (int rg = 0; rg < 4; rg++) {
                int m = wr * 64 + mi * 16 + lq * 4 + rg;
                int n = wc * 64 + ni * 16 + lr;
                sm[m * 128 + n] = f2b(acc[mi][ni][rg] + bv[ni]);
            }
    __syncthreads();
#pragma unroll
    for (int i = 0; i < 8; i++) {
        int idx = i * 2048 + tid * 8;
        int r = idx >> 7, c = idx & 127;
        *(u16x8*)(C + (rowBase + r) * N + colBase + c) = *(const u16x8*)&sm[idx];
    }
}

// Multi-segment GEMM: up to 3 independent GEMMs in ONE dispatch (disjoint
// outputs, inputs all finalized by earlier dispatches -> no coherence issues).
struct GSeg {
    const unsigned short* A;
    const unsigned short* B;
    const unsigned short* bias;
    unsigned short* C;
    float* Cf;
    int M, N, K, tiles, tilesX;
};

__global__ __launch_bounds__(256) void gemm_multi(GSeg s0, GSeg s1, GSeg s2,
                                                  const unsigned* __restrict__ fdt) {
    __shared__ unsigned short sm[16384];
    int b = blockIdx.x;
    const GSeg* s;
    int t;
    if (b < s0.tiles)                 { s = &s0; t = b; }
    else if (b < s0.tiles + s1.tiles) { s = &s1; t = b - s0.tiles; }
    else                              { s = &s2; t = b - s0.tiles - s1.tiles; }
    gemm_tile(s->A, s->B, s->bias, s->C, s->Cf, fdt,
              s->M, s->N, s->K, t % s->tilesX, t / s->tilesX, sm);
}

// ---------------------------------------------------------------------------
// GRU recurrence body — r13 kernel as a device function (split barrier:
// drain-sync -> thread0 fetch_add arrive -> overlapped Y/hn stores + gi
// prefetch -> thread0 spin -> sync).
// ---------------------------------------------------------------------------
DEVI void gru_body(
    const unsigned short* __restrict__ gi,   // [Tc][NB][G3]
    const unsigned short* __restrict__ Whh,  // [G3][HD]
    const unsigned short* __restrict__ bhh,  // [G3]
    const float* __restrict__ keep,          // [LSEQ][NB]
    const unsigned short* __restrict__ mem,  // [NB][1024]
    unsigned short* __restrict__ hdb,        // [2][NB][HD]
    unsigned short* __restrict__ Y,          // [Tc][NB][HD]
    unsigned short* __restrict__ hnB, float* __restrict__ hnF,
    bool f32out, int t0, int Tc, int layerOff,
    unsigned* __restrict__ ctr, int lb) {
    const int tid = threadIdx.x;
    const int l = tid & 63, w = tid >> 6, lr = l & 15, lq = l >> 4;
    const int bi = lb & 15, bj = lb >> 4;

    __shared__ float red[4][16][100];  // padded stride

    bf16x8 wreg[6][4];
#pragma unroll
    for (int fr = 0; fr < 6; fr++) {
        int g = fr >> 1, cf = fr & 1;
        long row = (long)g * HD + bj * 32 + cf * 16 + lr;
#pragma unroll
        for (int ks = 0; ks < 4; ks++) {
            int k = w * 128 + ks * 32 + lq * 8;
            wreg[fr][ks] = *(const bf16x8*)(Whh + row * HD + k);
        }
    }

    const int m = tid >> 4, c0 = (tid & 15) * 2;
    const int n_g = bi * 16 + m;
    const int ch = bj * 32 + c0;
    float bh[3][2];
#pragma unroll
    for (int g = 0; g < 3; g++) {
        unsigned v = *(const unsigned*)(bhh + g * HD + ch);
        bh[g][0] = b2f((unsigned short)(v & 0xffffu));
        bh[g][1] = b2f((unsigned short)(v >> 16));
    }

    if (t0 == 0) {  // init h0 from memory (layer slice) into parity 0
        unsigned v = *(const unsigned*)(mem + (long)n_g * 1024 + layerOff + ch);
        cstore((unsigned*)(hdb + (long)n_g * HD + ch), v);
        unsigned* islot = ctr + ((long)Tc * 16 + bi) * 32;
        __syncthreads();
        if (tid == 0) {
            __hip_atomic_fetch_add(islot, 1u, __ATOMIC_RELAXED, __HIP_MEMORY_SCOPE_AGENT);
            while (__hip_atomic_load(islot, __ATOMIC_RELAXED, __HIP_MEMORY_SCOPE_AGENT) < 16u)
                __builtin_amdgcn_s_sleep(1);
        }
        __syncthreads();
    }

    float hpv[2];
    {
        unsigned hp0 = cload((const unsigned*)(hdb + (long)(t0 & 1) * NB * HD + (long)n_g * HD + ch));
        hpv[0] = b2f((unsigned short)(hp0 & 0xffffu));
        hpv[1] = b2f((unsigned short)(hp0 >> 16));
    }

    unsigned gv[3];
    float kp;
    {
        const unsigned short* gp = gi + (long)n_g * G3;
#pragma unroll
        for (int g = 0; g < 3; g++) gv[g] = *(const unsigned*)(gp + g * HD + ch);
        kp = keep[(long)t0 * NB + n_g];
    }

    for (int t = t0; t < t0 + Tc; ++t) {
        const unsigned short* hc = hdb + (long)(t & 1) * NB * HD;
        unsigned short* hx = hdb + (long)((t + 1) & 1) * NB * HD;

        const unsigned* hrow = (const unsigned*)(hc + (long)(bi * 16 + lr) * HD);
        union { u32x4 u; bf16x8 v; } t0u, t1u, t2u, t3u;
        cload4x4(hrow + w * 64 + 0 * 16 + lq * 4, hrow + w * 64 + 1 * 16 + lq * 4,
                 hrow + w * 64 + 2 * 16 + lq * 4, hrow + w * 64 + 3 * 16 + lq * 4,
                 t0u.u, t1u.u, t2u.u, t3u.u);
        bf16x8 af[4] = { t0u.v, t1u.v, t2u.v, t3u.v };

        f32x4 acc[6] = {};
#pragma unroll
        for (int ks = 0; ks < 4; ks++)
#pragma unroll
            for (int fr = 0; fr < 6; fr++)
                acc[fr] = __builtin_amdgcn_mfma_f32_16x16x32_bf16(af[ks], wreg[fr][ks], acc[fr], 0, 0, 0);

#pragma unroll
        for (int fr = 0; fr < 6; fr++)
#pragma unroll
            for (int rg = 0; rg < 4; rg++)
                red[w][lq * 4 + rg][fr * 16 + lr] = acc[fr][rg];
        __syncthreads();

        float s[3][2];
#pragma unroll
        for (int g = 0; g < 3; g++) { s[g][0] = 0.f; s[g][1] = 0.f; }
#pragma unroll
        for (int ww = 0; ww < 4; ww++)
#pragma unroll
            for (int g = 0; g < 3; g++) {
                const float* p = &red[ww][m][g * 32 + c0];
                s[g][0] += p[0];
                s[g][1] += p[1];
            }

        unsigned short yo[2], ho[2];
        float hcf[2];
#pragma unroll
        for (int j = 0; j < 2; j++) {
            float ir  = b2f((unsigned short)((gv[0] >> (16 * j)) & 0xffffu));
            float iz  = b2f((unsigned short)((gv[1] >> (16 * j)) & 0xffffu));
            float in_ = b2f((unsigned short)((gv[2] >> (16 * j)) & 0xffffu));
            float r = 1.f / (1.f + __expf(-(ir + s[0][j] + bh[0][j])));
            float z = 1.f / (1.f + __expf(-(iz + s[1][j] + bh[1][j])));
            float nn = fast_tanh(in_ + r * (s[2][j] + bh[2][j]));
            float hnew = (1.f - z) * nn + z * hpv[j];
            hcf[j] = hnew * kp;
            yo[j] = f2b(hnew);
            ho[j] = f2b(hcf[j]);
            hpv[j] = b2f(ho[j]);
        }
        unsigned ypack = (unsigned)yo[0] | ((unsigned)yo[1] << 16);
        unsigned hpack = (unsigned)ho[0] | ((unsigned)ho[1] << 16);

        cstore((unsigned*)(hx + (long)n_g * HD + ch), hpack);  // barrier-gated

        const bool last = (t + 1 >= t0 + Tc);
        unsigned* slot = ctr + ((long)(t - t0) * 16 + bi) * 32;
        if (!last) {
            __syncthreads();  // drains the h cstore
            if (tid == 0)
                __hip_atomic_fetch_add(slot, 1u, __ATOMIC_RELAXED, __HIP_MEMORY_SCOPE_AGENT);
        }

        *(unsigned*)(Y + ((long)(t - t0) * NB + n_g) * HD + ch) = ypack;
        if (t == LSEQ - 1) {
            if (f32out) {
                hnF[(long)n_g * 1024 + layerOff + ch]     = hcf[0];
                hnF[(long)n_g * 1024 + layerOff + ch + 1] = hcf[1];
            } else {
                *(unsigned*)(hnB + (long)n_g * 1024 + layerOff + ch) = hpack;
            }
        }
        if (!last) {
            const unsigned short* gp = gi + ((long)(t + 1 - t0) * NB + n_g) * G3;
#pragma unroll
            for (int g = 0; g < 3; g++) gv[g] = *(const unsigned*)(gp + g * HD + ch);
            kp = keep[(long)(t + 1) * NB + n_g];
            if (tid == 0) {
                while (__hip_atomic_load(slot, __ATOMIC_RELAXED, __HIP_MEMORY_SCOPE_AGENT) < 16u)
                    __builtin_amdgcn_s_sleep(1);
            }
            __syncthreads();
        }
    }
}

// ---------------------------------------------------------------------------
// Dual-layer dispatch: blocks 0-255 = L0 chunk c, blocks 256-511 = L1 chunk
// c-1. Fully independent halves; 2 blocks/CU co-resident.
// ---------------------------------------------------------------------------
__global__ __launch_bounds__(256, 2) void gru_dual(
    const unsigned short* giA, const unsigned short* WhhA, const unsigned short* bhhA,
    unsigned short* hdbA, unsigned short* YA, int t0A, unsigned* ctrA, int enA,
    const unsigned short* giB, const unsigned short* WhhB, const unsigned short* bhhB,
    unsigned short* hdbB, unsigned short* YB, int t0B, unsigned* ctrB, int enB,
    const float* keep, const unsigned short* mem,
    unsigned short* hnB, float* hnF, const unsigned* fdt, int Tc) {
    const bool f32out = (*fdt != 0u);
    const int half = blockIdx.x >> 8;
    const int lb = blockIdx.x & 255;
    if (half == 0) {
        if (enA) gru_body(giA, WhhA, bhhA, keep, mem, hdbA, YA, hnB, hnF,
                          f32out, t0A, Tc, 0, ctrA, lb);
    } else {
        if (enB) gru_body(giB, WhhB, bhhB, keep, mem, hdbB, YB, hnB, hnF,
                          f32out, t0B, Tc, HD, ctrB, lb);
    }
}

// ---------------------------------------------------------------------------
// Host launcher — layer-pipelined duals + consolidated multi-GEMM.
// ---------------------------------------------------------------------------
extern "C" void kernel_launch(void* const* d_in, const int* in_sizes, int n_in,
                              void* d_out, int out_size, void* d_ws, size_t ws_size,
                              hipStream_t stream) {
    const void* x    = d_in[0];
    const void* mem  = d_in[1];
    const void* done = d_in[2];
    const void* fsrc[11] = { mem, d_in[3], d_in[4], d_in[5], d_in[6],
                             d_in[7], d_in[8], d_in[9], d_in[10], d_in[11], d_in[12] };
    const long  fn[11]   = { (long)NB * 1024, (long)G3 * CIN, (long)G3 * HD, G3, G3,
                             (long)G3 * HD, (long)G3 * HD, G3, G3, (long)NOUT * HD, NOUT };

    unsigned short* outB = (unsigned short*)d_out;
    float*          outF = (float*)d_out;
    unsigned short* hnB  = outB + (size_t)LSEQ * NB * NOUT;
    float*          hnF  = outF + (size_t)LSEQ * NB * NOUT;

    char* ws = (char*)d_ws;
    const size_t oFlag = 0;                                   // fdt @ +0, done-flag @ +64
    const size_t oKeep = 256;
    const size_t oCtr  = oKeep + (size_t)LSEQ * NB * 4;       // 8 MB barrier slots
    const size_t oWC   = oCtr + (size_t)8 * 1024 * 1024;      // staged weights/mem
    size_t wcTot = 0;
    size_t wcOff[11];
    for (int i = 0; i < 11; i++) { wcOff[i] = wcTot; wcTot += (size_t)fn[i] * 2; wcTot = (wcTot + 255) & ~(size_t)255; }
    const size_t oHdb0 = oWC + wcTot;
    const size_t oHdb1 = oHdb0 + (size_t)2 * NB * HD * 2;
    const size_t oDyn  = oHdb1 + (size_t)2 * NB * HD * 2;

    int Tc = 4;
    const int cand[6] = {128, 64, 32, 16, 8, 4};
    for (int i = 0; i < 6; i++) {
        size_t need = oDyn + (size_t)cand[i] * NB * (CIN + 2 * G3 + 2 * HD) * 2;
        if (need <= ws_size) { Tc = cand[i]; break; }
    }
    const size_t oXC  = oDyn;
    const size_t oGI0 = oXC + (size_t)Tc * NB * CIN * 2;
    const size_t oGI1 = oGI0 + (size_t)Tc * NB * G3 * 2;
    const size_t oY0c = oGI1 + (size_t)Tc * NB * G3 * 2;
    const size_t oY1c = oY0c + (size_t)Tc * NB * HD * 2;

    unsigned*       FDT  = (unsigned*)(ws + oFlag);
    unsigned*       DFLG = (unsigned*)(ws + oFlag + 64);
    float*          KEEP = (float*)(ws + oKeep);
    unsigned*       CTR  = (unsigned*)(ws + oCtr);
    unsigned short* WC   = (unsigned short*)(ws + oWC);
    unsigned short* HDB0 = (unsigned short*)(ws + oHdb0);
    unsigned short* HDB1 = (unsigned short*)(ws + oHdb1);
    unsigned short* XC   = (unsigned short*)(ws + oXC);
    unsigned short* GI0  = (unsigned short*)(ws + oGI0);
    unsigned short* GI1  = (unsigned short*)(ws + oGI1);
    unsigned short* Y0c  = (unsigned short*)(ws + oY0c);
    unsigned short* Y1c  = (unsigned short*)(ws + oY1c);

    unsigned short* MEMc = WC + wcOff[0] / 2;
    unsigned short* WIH0 = WC + wcOff[1] / 2;
    unsigned short* WHH0 = WC + wcOff[2] / 2;
    unsigned short* BIH0 = WC + wcOff[3] / 2;
    unsigned short* BHH0 = WC + wcOff[4] / 2;
    unsigned short* WIH1 = WC + wcOff[5] / 2;
    unsigned short* WHH1 = WC + wcOff[6] / 2;
    unsigned short* BIH1 = WC + wcOff[7] / 2;
    unsigned short* BHH1 = WC + wcOff[8] / 2;
    unsigned short* WPc  = WC + wcOff[9] / 2;
    unsigned short* BPc  = WC + wcOff[10] / 2;

    hipMemsetAsync(ws + oCtr, 0, (size_t)8 * 1024 * 1024, stream);
    detect_fdt<<<1, 256, 0, stream>>>((const unsigned short*)x, 4096, FDT);
    detect_done<<<1, 256, 0, stream>>>((const unsigned char*)done, in_sizes[2], DFLG);
    expand_done<<<(LSEQ * NB + 255) / 256, 256, 0, stream>>>(done, DFLG, KEEP, LSEQ * NB);

    for (int i = 0; i < 11; i++) {
        int blocks = (int)((fn[i] + 1023) / 1024);
        if (blocks > 2048) blocks = 2048;
        cast_bf16<<<blocks, 256, 0, stream>>>(fsrc[i], 0, WC + wcOff[i] / 2, fn[i], FDT);
    }

    const int NC = LSEQ / Tc;
    const size_t SZ = (size_t)(Tc + 2) * 16 * 32;  // ctr region dwords per instance
    const long giN = (long)Tc * NB * CIN;
    const int MT = Tc * NB / 128;                  // M-tiles per chunk GEMM
    const GSeg ZSEG = { nullptr, nullptr, nullptr, nullptr, nullptr, 0, 0, 0, 0, 1 };

    // prologue: GI0 for chunk 0
    cast_bf16<<<2048, 256, 0, stream>>>(x, 0, XC, giN, FDT);
    {
        GSeg s0 = ZSEG, s1 = ZSEG;
        GSeg s2 = { XC, WIH0, BIH0, GI0, nullptr, Tc * NB, G3, CIN, MT * (G3 / 128), G3 / 128 };
        gemm_multi<<<s2.tiles, 256, 0, stream>>>(s0, s1, s2, FDT);
    }

    for (int it = 0; it <= NC; ++it) {
        const int cA = it, cB = it - 1;
        const int enA = (cA < NC) ? 1 : 0;
        const int enB = (cB >= 0) ? 1 : 0;

        gru_dual<<<512, 256, 0, stream>>>(
            GI0, WHH0, BHH0, HDB0, Y0c, cA * Tc, CTR + (size_t)(2 * it) * SZ, enA,
            GI1, WHH1, BHH1, HDB1, Y1c, cB * Tc, CTR + (size_t)(2 * it + 1) * SZ, enB,
            KEEP, MEMc, hnB, hnF, FDT, Tc);

        // consolidated GEMMs: gemm1(cA) + proj(cB) + gemm0(cA+1), one dispatch
        const int doG0 = (cA + 1 < NC) ? 1 : 0;
        if (doG0)
            cast_bf16<<<2048, 256, 0, stream>>>(x, (long)(cA + 1) * Tc * NB * CIN, XC, giN, FDT);

        GSeg s0 = ZSEG, s1 = ZSEG, s2 = ZSEG;
        if (enA)
            s0 = GSeg{ Y0c, WIH1, BIH1, GI1, nullptr, Tc * NB, G3, HD, MT * (G3 / 128), G3 / 128 };
        if (enB)
            s1 = GSeg{ Y1c, WPc, BPc, outB + (size_t)cB * Tc * NB * NOUT,
                       outF + (size_t)cB * Tc * NB * NOUT, Tc * NB, NOUT, HD,
                       MT * (NOUT / 128), NOUT / 128 };
        if (doG0)
            s2 = GSeg{ XC, WIH0, BIH0, GI0, nullptr, Tc * NB, G3, CIN, MT * (G3 / 128), G3 / 128 };
        const int total = s0.tiles + s1.tiles + s2.tiles;
        if (total)
            gemm_multi<<<total, 256, 0, stream>>>(s0, s1, s2, FDT);
    }
}